// Round 4
// baseline (383.594 us; speedup 1.0000x reference)
//
#include <hip/hip_runtime.h>

#define M_DIM 4096
#define N_DIM 4096
#define K_DIM 4096

typedef float f32x4 __attribute__((ext_vector_type(4)));
typedef __bf16 bf16x8 __attribute__((ext_vector_type(8)));

// round-to-nearest-even fp32 -> bf16
__device__ __forceinline__ unsigned short f2b(float f) {
    unsigned int u = __float_as_uint(f);
    u += 0x7fffu + ((u >> 16) & 1u);
    return (unsigned short)(u >> 16);
}

// Arithmetic NVFP4 (e2m1) decode — pure VALU, bit-exact vs the codebook.
__device__ __forceinline__ float nvfp4_decode(int n) {
    unsigned m = (unsigned)n & 7u;
    unsigned e = m >> 1, f = m & 1u;
    unsigned bits = (m >= 2u) ? (((126u + e) << 23) | (f << 22))
                              : (m * 0x3f000000u);   // 0 -> 0.0f, 1 -> 0.5f
    bits |= ((unsigned)n & 8u) << 28;                 // sign
    return __uint_as_float(bits);
}

// ---------------------------------------------------------------------------
// Merged prep kernel.
//   blocks [0, 8192)      : x fp32 -> bf16  (8 elems/thread)
//   blocks [8192, 12288)  : build permuted+dequantized W_bf16 [N,K]
// ---------------------------------------------------------------------------
__global__ __launch_bounds__(256) void prep_kernel(
        const float* __restrict__ x, unsigned short* __restrict__ xb,
        const int* __restrict__ idx4, const float* __restrict__ sc4,
        const float* __restrict__ gs4, const float* __restrict__ w8,
        const float* __restrict__ s8, const float* __restrict__ w16,
        const int* __restrict__ iperm, unsigned short* __restrict__ W) {
    const int b = blockIdx.x;
    if (b < 8192) {
        size_t i = ((size_t)b * 256 + threadIdx.x) * 8;
        float4 a0 = *(const float4*)(x + i);
        float4 a1 = *(const float4*)(x + i + 4);
        union { unsigned short h[8]; uint4 u; } o;
        o.h[0] = f2b(a0.x); o.h[1] = f2b(a0.y); o.h[2] = f2b(a0.z); o.h[3] = f2b(a0.w);
        o.h[4] = f2b(a1.x); o.h[5] = f2b(a1.y); o.h[6] = f2b(a1.z); o.h[7] = f2b(a1.w);
        *(uint4*)(xb + i) = o.u;
        return;
    }
    const int j = b - 8192;
    const int t = threadIdx.x;
    const int g = iperm[j];

#pragma unroll
    for (int h = 0; h < 2; ++h) {
        const int k0 = h * 2048 + t * 8;   // 8 elems / thread / half
        union { unsigned short hh[8]; uint4 u; } o;
        if (g < 2048) {
            const float s = sc4[(size_t)g * (K_DIM / 16) + (k0 >> 4)] * gs4[0];
            const int4* ip = (const int4*)(idx4 + (size_t)g * K_DIM + k0);
            int4 v0 = ip[0], v1 = ip[1];
            o.hh[0] = f2b(nvfp4_decode(v0.x) * s);
            o.hh[1] = f2b(nvfp4_decode(v0.y) * s);
            o.hh[2] = f2b(nvfp4_decode(v0.z) * s);
            o.hh[3] = f2b(nvfp4_decode(v0.w) * s);
            o.hh[4] = f2b(nvfp4_decode(v1.x) * s);
            o.hh[5] = f2b(nvfp4_decode(v1.y) * s);
            o.hh[6] = f2b(nvfp4_decode(v1.z) * s);
            o.hh[7] = f2b(nvfp4_decode(v1.w) * s);
        } else if (g < 3072) {
            const float s = s8[0];
            const float4* wp = (const float4*)(w8 + (size_t)(g - 2048) * K_DIM + k0);
            float4 v0 = wp[0], v1 = wp[1];
            o.hh[0] = f2b(v0.x * s); o.hh[1] = f2b(v0.y * s);
            o.hh[2] = f2b(v0.z * s); o.hh[3] = f2b(v0.w * s);
            o.hh[4] = f2b(v1.x * s); o.hh[5] = f2b(v1.y * s);
            o.hh[6] = f2b(v1.z * s); o.hh[7] = f2b(v1.w * s);
        } else {
            const float4* wp = (const float4*)(w16 + (size_t)(g - 3072) * K_DIM + k0);
            float4 v0 = wp[0], v1 = wp[1];
            o.hh[0] = f2b(v0.x); o.hh[1] = f2b(v0.y);
            o.hh[2] = f2b(v0.z); o.hh[3] = f2b(v0.w);
            o.hh[4] = f2b(v1.x); o.hh[5] = f2b(v1.y);
            o.hh[6] = f2b(v1.z); o.hh[7] = f2b(v1.w);
        }
        *(uint4*)(W + (size_t)j * K_DIM + k0) = o.u;
    }
}

// ---------------------------------------------------------------------------
// GEMM: C[M,N] = Xb[M,K] * Wb[N,K]^T + bias
// 128x128 tile, BK=32, 4 waves 2x2, 4x4 frags of mfma_f32_16x16x32_bf16.
// Double-buffered LDS, ONE barrier per K-iter: barrier drains tile-k DMA
// (issued a full compute-phase ago), then tile-k+1 DMA is issued into the
// other buffer and overlaps this iteration's ds_read+MFMA.
// XOR bank swizzle: logical 16B chunk kc of row r stored at physical chunk
// kc ^ ((r>>1)&3)  ->  fragment reads hit all 8 LDS bank-groups, 2-way (free).
// ---------------------------------------------------------------------------
#define GLOAD_LDS16(g, l)                                                     \
    __builtin_amdgcn_global_load_lds(                                         \
        (const __attribute__((address_space(1))) void*)(unsigned long long)(g),\
        (__attribute__((address_space(3))) void*)(unsigned int)(unsigned long long)(l), \
        16, 0, 0)

__global__ __launch_bounds__(256) void gemm_kernel(
        const unsigned short* __restrict__ X, const unsigned short* __restrict__ W,
        const float* __restrict__ bias, float* __restrict__ C) {
    __shared__ __align__(16) unsigned short As[2][128 * 32];
    __shared__ __align__(16) unsigned short Bs[2][128 * 32];

    // XCD-aware supertile swizzle (kept from R2: 205 -> 197 us)
    const int pid = blockIdx.x;
    const int GROUP = 8;
    const int group_sz = GROUP * (N_DIM / 128);        // 256
    const int grp = pid / group_sz;
    const int rem = pid % group_sz;
    const int bm = grp * GROUP + (rem % GROUP);
    const int bn = rem / GROUP;
    const int m0 = bm * 128;
    const int n0 = bn * 128;

    const int tid  = threadIdx.x;
    const int wave = tid >> 6;
    const int lane = tid & 63;
    const int quad = lane >> 4;
    const int l16  = lane & 15;
    const int wr   = wave >> 1;
    const int wc   = wave & 1;

    // staging: physical chunk c holds logical chunk (c&3)^((row>>1)&3) of row c>>2
    const int c0 = wave * 64 + lane;   // 0..255
    const int c1 = c0 + 256;           // 256..511
    const int rA0 = c0 >> 2, kcs0 = ((c0 & 3) ^ ((rA0 >> 1) & 3)) * 8;
    const int rA1 = c1 >> 2, kcs1 = ((c1 & 3) ^ ((rA1 >> 1) & 3)) * 8;

    const unsigned short* Xa0 = X + (size_t)(m0 + rA0) * K_DIM + kcs0;
    const unsigned short* Xa1 = X + (size_t)(m0 + rA1) * K_DIM + kcs1;
    const unsigned short* Wb0 = W + (size_t)(n0 + rA0) * K_DIM + kcs0;
    const unsigned short* Wb1 = W + (size_t)(n0 + rA1) * K_DIM + kcs1;

    // fragment-read physical chunk: quad ^ ((row>>1)&3); row base is a
    // multiple of 16 so (row>>1)&3 == (l16>>1)&3 for all i
    const int pcr = (quad ^ ((l16 >> 1) & 3)) * 8;

    f32x4 acc[4][4] = {};

    // prologue: tile 0 -> buffer 0
    GLOAD_LDS16(Xa0, &As[0][c0 * 8]);
    GLOAD_LDS16(Xa1, &As[0][c1 * 8]);
    GLOAD_LDS16(Wb0, &Bs[0][c0 * 8]);
    GLOAD_LDS16(Wb1, &Bs[0][c1 * 8]);

    const int NT = K_DIM / 32;
    for (int kt = 0; kt < NT; ++kt) {
        const int cur = kt & 1;
        __syncthreads();                    // tile-kt DMA done; all reads of buf cur^1 done
        if (kt + 1 < NT) {
            const int k0 = (kt + 1) * 32;
            const int nxt = cur ^ 1;
            GLOAD_LDS16(Xa0 + k0, &As[nxt][c0 * 8]);
            GLOAD_LDS16(Xa1 + k0, &As[nxt][c1 * 8]);
            GLOAD_LDS16(Wb0 + k0, &Bs[nxt][c0 * 8]);
            GLOAD_LDS16(Wb1 + k0, &Bs[nxt][c1 * 8]);
        }

        bf16x8 af[4], bq[4];
#pragma unroll
        for (int i = 0; i < 4; ++i)
            af[i] = *(const bf16x8*)&As[cur][(wr * 64 + i * 16 + l16) * 32 + pcr];
#pragma unroll
        for (int jj = 0; jj < 4; ++jj)
            bq[jj] = *(const bf16x8*)&Bs[cur][(wc * 64 + jj * 16 + l16) * 32 + pcr];

#pragma unroll
        for (int i = 0; i < 4; ++i)
#pragma unroll
            for (int jj = 0; jj < 4; ++jj)
                acc[i][jj] = __builtin_amdgcn_mfma_f32_16x16x32_bf16(
                    af[i], bq[jj], acc[i][jj], 0, 0, 0);
    }

    // epilogue: C/D layout col=lane&15, row=(lane>>4)*4+reg
#pragma unroll
    for (int jj = 0; jj < 4; ++jj) {
        const int col = n0 + wc * 64 + jj * 16 + l16;
        const float bv = bias[col];
#pragma unroll
        for (int i = 0; i < 4; ++i) {
            const int rowb = m0 + wr * 64 + i * 16 + quad * 4;
#pragma unroll
            for (int r = 0; r < 4; ++r)
                C[(size_t)(rowb + r) * N_DIM + col] = acc[i][jj][r] + bv;
        }
    }
}

// ---------------------------------------------------------------------------
extern "C" void kernel_launch(void* const* d_in, const int* in_sizes, int n_in,
                              void* d_out, int out_size, void* d_ws, size_t ws_size,
                              hipStream_t stream) {
    const float* x            = (const float*)d_in[0];
    const int*   nvfp4_idx    = (const int*)d_in[1];
    const float* nvfp4_scales = (const float*)d_in[2];
    const float* gscale       = (const float*)d_in[3];
    const float* w_fp8        = (const float*)d_in[4];
    const float* fp8_scale    = (const float*)d_in[5];
    const float* w_fp16       = (const float*)d_in[6];
    const float* bias         = (const float*)d_in[7];
    const int*   inv_perm     = (const int*)d_in[8];
    float* out = (float*)d_out;

    unsigned short* xb = (unsigned short*)d_ws;                 // 32 MiB
    unsigned short* wb = xb + (size_t)M_DIM * K_DIM;            // 32 MiB

    prep_kernel<<<8192 + 4096, 256, 0, stream>>>(x, xb, nvfp4_idx, nvfp4_scales,
                                                 gscale, w_fp8, fp8_scale, w_fp16,
                                                 inv_perm, wb);
    gemm_kernel<<<(M_DIM / 128) * (N_DIM / 128), 256, 0, stream>>>(xb, wb, bias, out);
}

// Round 5
// 358.742 us; speedup vs baseline: 1.0693x; 1.0693x over previous
//
#include <hip/hip_runtime.h>

#define M_DIM 4096
#define N_DIM 4096
#define K_DIM 4096

typedef float f32x4 __attribute__((ext_vector_type(4)));
typedef __bf16 bf16x8 __attribute__((ext_vector_type(8)));

// round-to-nearest-even fp32 -> bf16
__device__ __forceinline__ unsigned short f2b(float f) {
    unsigned int u = __float_as_uint(f);
    u += 0x7fffu + ((u >> 16) & 1u);
    return (unsigned short)(u >> 16);
}

// Arithmetic NVFP4 (e2m1) decode — pure VALU, bit-exact vs the codebook.
__device__ __forceinline__ float nvfp4_decode(int n) {
    unsigned m = (unsigned)n & 7u;
    unsigned e = m >> 1, f = m & 1u;
    unsigned bits = (m >= 2u) ? (((126u + e) << 23) | (f << 22))
                              : (m * 0x3f000000u);   // 0 -> 0.0f, 1 -> 0.5f
    bits |= ((unsigned)n & 8u) << 28;                 // sign
    return __uint_as_float(bits);
}

// ---------------------------------------------------------------------------
// Merged prep kernel.
//   blocks [0, 8192)      : x fp32 -> bf16  (8 elems/thread)
//   blocks [8192, 12288)  : build permuted+dequantized W_bf16 [N,K]
// ---------------------------------------------------------------------------
__global__ __launch_bounds__(256) void prep_kernel(
        const float* __restrict__ x, unsigned short* __restrict__ xb,
        const int* __restrict__ idx4, const float* __restrict__ sc4,
        const float* __restrict__ gs4, const float* __restrict__ w8,
        const float* __restrict__ s8, const float* __restrict__ w16,
        const int* __restrict__ iperm, unsigned short* __restrict__ W) {
    const int b = blockIdx.x;
    if (b < 8192) {
        size_t i = ((size_t)b * 256 + threadIdx.x) * 8;
        float4 a0 = *(const float4*)(x + i);
        float4 a1 = *(const float4*)(x + i + 4);
        union { unsigned short h[8]; uint4 u; } o;
        o.h[0] = f2b(a0.x); o.h[1] = f2b(a0.y); o.h[2] = f2b(a0.z); o.h[3] = f2b(a0.w);
        o.h[4] = f2b(a1.x); o.h[5] = f2b(a1.y); o.h[6] = f2b(a1.z); o.h[7] = f2b(a1.w);
        *(uint4*)(xb + i) = o.u;
        return;
    }
    const int j = b - 8192;
    const int t = threadIdx.x;
    const int g = iperm[j];

#pragma unroll
    for (int h = 0; h < 2; ++h) {
        const int k0 = h * 2048 + t * 8;   // 8 elems / thread / half
        union { unsigned short hh[8]; uint4 u; } o;
        if (g < 2048) {
            const float s = sc4[(size_t)g * (K_DIM / 16) + (k0 >> 4)] * gs4[0];
            const int4* ip = (const int4*)(idx4 + (size_t)g * K_DIM + k0);
            int4 v0 = ip[0], v1 = ip[1];
            o.hh[0] = f2b(nvfp4_decode(v0.x) * s);
            o.hh[1] = f2b(nvfp4_decode(v0.y) * s);
            o.hh[2] = f2b(nvfp4_decode(v0.z) * s);
            o.hh[3] = f2b(nvfp4_decode(v0.w) * s);
            o.hh[4] = f2b(nvfp4_decode(v1.x) * s);
            o.hh[5] = f2b(nvfp4_decode(v1.y) * s);
            o.hh[6] = f2b(nvfp4_decode(v1.z) * s);
            o.hh[7] = f2b(nvfp4_decode(v1.w) * s);
        } else if (g < 3072) {
            const float s = s8[0];
            const float4* wp = (const float4*)(w8 + (size_t)(g - 2048) * K_DIM + k0);
            float4 v0 = wp[0], v1 = wp[1];
            o.hh[0] = f2b(v0.x * s); o.hh[1] = f2b(v0.y * s);
            o.hh[2] = f2b(v0.z * s); o.hh[3] = f2b(v0.w * s);
            o.hh[4] = f2b(v1.x * s); o.hh[5] = f2b(v1.y * s);
            o.hh[6] = f2b(v1.z * s); o.hh[7] = f2b(v1.w * s);
        } else {
            const float4* wp = (const float4*)(w16 + (size_t)(g - 3072) * K_DIM + k0);
            float4 v0 = wp[0], v1 = wp[1];
            o.hh[0] = f2b(v0.x); o.hh[1] = f2b(v0.y);
            o.hh[2] = f2b(v0.z); o.hh[3] = f2b(v0.w);
            o.hh[4] = f2b(v1.x); o.hh[5] = f2b(v1.y);
            o.hh[6] = f2b(v1.z); o.hh[7] = f2b(v1.w);
        }
        *(uint4*)(W + (size_t)j * K_DIM + k0) = o.u;
    }
}

// ---------------------------------------------------------------------------
// GEMM: C[M,N] = Xb[M,K] * Wb[N,K]^T + bias
// R2's two-barrier single-buffer m97 loop (best: 197us, VALU 11%)
//   + R4's XOR bank swizzle (verified: SQ_LDS_BANK_CONFLICT -> 0).
// 128x128 tile, BK=32, 4 waves 2x2, 4x4 frags of mfma_f32_16x16x32_bf16,
// global_load_lds width-16 staging, XCD supertile swizzle.
// Swizzle: logical 16B chunk kc of row r lives at physical chunk
// kc ^ ((r>>1)&3)  ->  fragment reads hit all 8 LDS bank-groups, 2-way (free).
// ---------------------------------------------------------------------------
#define GLOAD_LDS16(g, l)                                                     \
    __builtin_amdgcn_global_load_lds(                                         \
        (const __attribute__((address_space(1))) void*)(unsigned long long)(g),\
        (__attribute__((address_space(3))) void*)(unsigned int)(unsigned long long)(l), \
        16, 0, 0)

__global__ __launch_bounds__(256) void gemm_kernel(
        const unsigned short* __restrict__ X, const unsigned short* __restrict__ W,
        const float* __restrict__ bias, float* __restrict__ C) {
    __shared__ __align__(16) unsigned short As[128 * 32];
    __shared__ __align__(16) unsigned short Bs[128 * 32];

    // XCD-aware supertile swizzle (kept from R2: 205 -> 197 us)
    const int pid = blockIdx.x;
    const int GROUP = 8;
    const int group_sz = GROUP * (N_DIM / 128);        // 256
    const int grp = pid / group_sz;
    const int rem = pid % group_sz;
    const int bm = grp * GROUP + (rem % GROUP);
    const int bn = rem / GROUP;
    const int m0 = bm * 128;
    const int n0 = bn * 128;

    const int tid  = threadIdx.x;
    const int wave = tid >> 6;
    const int lane = tid & 63;
    const int quad = lane >> 4;
    const int l16  = lane & 15;
    const int wr   = wave >> 1;
    const int wc   = wave & 1;

    // staging: physical chunk c holds logical chunk (c&3)^((row>>1)&3) of row c>>2
    const int c0 = wave * 64 + lane;   // 0..255
    const int c1 = c0 + 256;           // 256..511
    const int rA0 = c0 >> 2, kcs0 = ((c0 & 3) ^ ((rA0 >> 1) & 3)) * 8;
    const int rA1 = c1 >> 2, kcs1 = ((c1 & 3) ^ ((rA1 >> 1) & 3)) * 8;

    const unsigned short* Xa0 = X + (size_t)(m0 + rA0) * K_DIM + kcs0;
    const unsigned short* Xa1 = X + (size_t)(m0 + rA1) * K_DIM + kcs1;
    const unsigned short* Wb0 = W + (size_t)(n0 + rA0) * K_DIM + kcs0;
    const unsigned short* Wb1 = W + (size_t)(n0 + rA1) * K_DIM + kcs1;

    // fragment-read physical chunk: quad ^ ((row>>1)&3); row base is a
    // multiple of 16 so (row>>1)&3 == (l16>>1)&3 for all i
    const int pcr = (quad ^ ((l16 >> 1) & 3)) * 8;

    f32x4 acc[4][4] = {};

    for (int kt = 0; kt < K_DIM / 32; ++kt) {
        const int k0 = kt * 32;
        GLOAD_LDS16(Xa0 + k0, &As[c0 * 8]);
        GLOAD_LDS16(Xa1 + k0, &As[c1 * 8]);
        GLOAD_LDS16(Wb0 + k0, &Bs[c0 * 8]);
        GLOAD_LDS16(Wb1 + k0, &Bs[c1 * 8]);
        __syncthreads();

        bf16x8 af[4], bq[4];
#pragma unroll
        for (int i = 0; i < 4; ++i)
            af[i] = *(const bf16x8*)&As[(wr * 64 + i * 16 + l16) * 32 + pcr];
#pragma unroll
        for (int jj = 0; jj < 4; ++jj)
            bq[jj] = *(const bf16x8*)&Bs[(wc * 64 + jj * 16 + l16) * 32 + pcr];

#pragma unroll
        for (int i = 0; i < 4; ++i)
#pragma unroll
            for (int jj = 0; jj < 4; ++jj)
                acc[i][jj] = __builtin_amdgcn_mfma_f32_16x16x32_bf16(
                    af[i], bq[jj], acc[i][jj], 0, 0, 0);

        __syncthreads();
    }

    // epilogue: C/D layout col=lane&15, row=(lane>>4)*4+reg
#pragma unroll
    for (int jj = 0; jj < 4; ++jj) {
        const int col = n0 + wc * 64 + jj * 16 + l16;
        const float bv = bias[col];
#pragma unroll
        for (int i = 0; i < 4; ++i) {
            const int rowb = m0 + wr * 64 + i * 16 + quad * 4;
#pragma unroll
            for (int r = 0; r < 4; ++r)
                C[(size_t)(rowb + r) * N_DIM + col] = acc[i][jj][r] + bv;
        }
    }
}

// ---------------------------------------------------------------------------
extern "C" void kernel_launch(void* const* d_in, const int* in_sizes, int n_in,
                              void* d_out, int out_size, void* d_ws, size_t ws_size,
                              hipStream_t stream) {
    const float* x            = (const float*)d_in[0];
    const int*   nvfp4_idx    = (const int*)d_in[1];
    const float* nvfp4_scales = (const float*)d_in[2];
    const float* gscale       = (const float*)d_in[3];
    const float* w_fp8        = (const float*)d_in[4];
    const float* fp8_scale    = (const float*)d_in[5];
    const float* w_fp16       = (const float*)d_in[6];
    const float* bias         = (const float*)d_in[7];
    const int*   inv_perm     = (const int*)d_in[8];
    float* out = (float*)d_out;

    unsigned short* xb = (unsigned short*)d_ws;                 // 32 MiB
    unsigned short* wb = xb + (size_t)M_DIM * K_DIM;            // 32 MiB

    prep_kernel<<<8192 + 4096, 256, 0, stream>>>(x, xb, nvfp4_idx, nvfp4_scales,
                                                 gscale, w_fp8, fp8_scale, w_fp16,
                                                 inv_perm, wb);
    gemm_kernel<<<(M_DIM / 128) * (N_DIM / 128), 256, 0, stream>>>(xb, wb, bias, out);
}